// Round 12
// baseline (264.729 us; speedup 1.0000x reference)
//
#include <hip/hip_runtime.h>

typedef __attribute__((ext_vector_type(8))) short bf16x8;
typedef __attribute__((ext_vector_type(4))) float f32x4;

#define NBLK   16          // nodes per tile
#define DIMF   1152        // floats per node row
#define NTILE  6250        // 100000 / 16, exact
#define GRIDSZ 512         // persistent, stride grid
#define ROWU   1160        // padded ushort stride per node row

// round-to-nearest-even f32 -> bf16 bits (no NaNs in this data)
static __device__ __forceinline__ unsigned short f2bf(float f) {
    unsigned int u = __builtin_bit_cast(unsigned int, f);
    return (unsigned short)((u + 0x7FFFu + ((u >> 16) & 1u)) >> 16);
}

__global__ __launch_bounds__(512, 4)   // 4 waves/EU = 2 blocks/CU -> 128-reg budget
void seglin_kernel(const float* __restrict__ x, const float* __restrict__ w,
                   const float* __restrict__ b, float* __restrict__ out) {
    // LDS: per node, 9 planes of 128 u-contiguous bf16
    //   plane 0 = seg0; planes 1..3 = seg1 (base 128+i*128); planes 4..8 = seg2 (base 512+i*128)
    __shared__ unsigned short xs[2][NBLK][ROWU];

    const int tid  = threadIdx.x;
    const int wv   = tid >> 6;
    const int lane = tid & 63;
    const int lq   = lane & 15;       // node col n (B); A row v_local (W frags)
    const int lg   = lane >> 4;       // k-group 0..3
    const int v0   = wv * 16;

    const int sn = tid >> 5;          // staging node 0..15
    const int st = tid & 31;          // staging u-chunk 0..31

    const float pw = 0.08838834764831845f;  // 128^-0.5, folded into W

    // ---- hoist A = pw * W^T fragments (once per block) ----
    bf16x8 wf[3][4];
    const int woff[3] = {0, 16384, 32768};
    #pragma unroll
    for (int s = 0; s < 3; ++s)
        #pragma unroll
        for (int t = 0; t < 4; ++t) {
            bf16x8 f;
            #pragma unroll
            for (int e = 0; e < 8; ++e) {
                int u = 32 * t + lg * 8 + e;
                f[e] = (short)f2bf(pw * w[woff[s] + u * 128 + v0 + lq]);
            }
            wf[s][t] = f;
        }

    float biasr[4];
    #pragma unroll
    for (int e = 0; e < 4; ++e) biasr[e] = b[v0 + lg * 4 + e];

    // Staged tile, HALVED live ranges to fit 2 blocks/CU in registers:
    //   H1 = seg0+seg1 (16 f32): load at loop-top, retire after compute A+B
    //   H2 = seg2      (20 f32): load mid-tile,  retire at loop-end
    // Each keeps >= half-tile (~9K cyc) between issue and vmcnt consumption.
    float4 g0, g1[3];
    float4 g2[5];

#define STAGE_LOAD_H1(TILE) do {                                                \
        const float* src = x + ((long)(TILE) * NBLK + sn) * DIMF;               \
        g0    = *reinterpret_cast<const float4*>(src + 4 * st);                 \
        g1[0] = *reinterpret_cast<const float4*>(src + 128 + 12 * st);          \
        g1[1] = *reinterpret_cast<const float4*>(src + 128 + 12 * st + 4);      \
        g1[2] = *reinterpret_cast<const float4*>(src + 128 + 12 * st + 8);      \
    } while (0)

#define STAGE_LOAD_H2(TILE) do {                                                \
        const float* src = x + ((long)(TILE) * NBLK + sn) * DIMF;               \
        g2[0] = *reinterpret_cast<const float4*>(src + 512 + 20 * st);          \
        g2[1] = *reinterpret_cast<const float4*>(src + 512 + 20 * st + 4);      \
        g2[2] = *reinterpret_cast<const float4*>(src + 512 + 20 * st + 8);      \
        g2[3] = *reinterpret_cast<const float4*>(src + 512 + 20 * st + 12);     \
        g2[4] = *reinterpret_cast<const float4*>(src + 512 + 20 * st + 16);     \
    } while (0)

    // seg1 value at plane i, pos u=4st+e is src[128 + 12st + 3e + i] = f1[3e+i]
#define STAGE_WRITE_H1(BUF) do {                                                \
        unsigned short* dst = &xs[BUF][sn][0];                                  \
        { ushort4 h;                                                            \
          h.x = f2bf(g0.x); h.y = f2bf(g0.y); h.z = f2bf(g0.z); h.w = f2bf(g0.w); \
          *reinterpret_cast<ushort4*>(dst + 4 * st) = h; }                      \
        float f1[12];                                                           \
        f1[0]=g1[0].x; f1[1]=g1[0].y; f1[2]=g1[0].z; f1[3]=g1[0].w;             \
        f1[4]=g1[1].x; f1[5]=g1[1].y; f1[6]=g1[1].z; f1[7]=g1[1].w;             \
        f1[8]=g1[2].x; f1[9]=g1[2].y; f1[10]=g1[2].z; f1[11]=g1[2].w;           \
        _Pragma("unroll")                                                       \
        for (int i = 0; i < 3; ++i) {                                           \
            ushort4 h;                                                          \
            h.x = f2bf(f1[0 + i]); h.y = f2bf(f1[3 + i]);                       \
            h.z = f2bf(f1[6 + i]); h.w = f2bf(f1[9 + i]);                       \
            *reinterpret_cast<ushort4*>(dst + 128 + (i << 7) + 4 * st) = h;     \
        }                                                                       \
    } while (0)

    // seg2 value at plane i, pos u=4st+e is src[512 + 20st + 5e + i] = f2[5e+i]
#define STAGE_WRITE_H2(BUF) do {                                                \
        unsigned short* dst = &xs[BUF][sn][0];                                  \
        float f2[20];                                                           \
        f2[0]=g2[0].x; f2[1]=g2[0].y; f2[2]=g2[0].z; f2[3]=g2[0].w;             \
        f2[4]=g2[1].x; f2[5]=g2[1].y; f2[6]=g2[1].z; f2[7]=g2[1].w;             \
        f2[8]=g2[2].x; f2[9]=g2[2].y; f2[10]=g2[2].z; f2[11]=g2[2].w;           \
        f2[12]=g2[3].x; f2[13]=g2[3].y; f2[14]=g2[3].z; f2[15]=g2[3].w;         \
        f2[16]=g2[4].x; f2[17]=g2[4].y; f2[18]=g2[4].z; f2[19]=g2[4].w;         \
        _Pragma("unroll")                                                       \
        for (int i = 0; i < 5; ++i) {                                           \
            ushort4 h;                                                          \
            h.x = f2bf(f2[0 + i]);  h.y = f2bf(f2[5 + i]);                      \
            h.z = f2bf(f2[10 + i]); h.w = f2bf(f2[15 + i]);                     \
            *reinterpret_cast<ushort4*>(dst + 512 + (i << 7) + 4 * st) = h;     \
        }                                                                       \
    } while (0)

    // ---- prologue ----
    long tile = blockIdx.x;
    STAGE_LOAD_H1(tile);
    STAGE_WRITE_H1(0);
    STAGE_LOAD_H2(tile);
    STAGE_WRITE_H2(0);
    __syncthreads();

    int cur = 0;
    for (; tile < NTILE; tile += GRIDSZ) {
        const bool has_next = (tile + GRIDSZ) < NTILE;

        // H1 loads for next tile: issued first, consumed after compute A+B
        if (has_next) STAGE_LOAD_H1(tile + GRIDSZ);

        const unsigned short* row = &xs[cur][lq][0];
        float* orow = out + (tile * NBLK + lq) * (long)DIMF;
        const int vb = v0 + lg * 4;

        // ===== group A: seg0 — acc live: 4 f32 =====
        {
            f32x4 a0 = {0.f, 0.f, 0.f, 0.f};
            #pragma unroll
            for (int t = 0; t < 4; ++t) {
                bf16x8 bf = *reinterpret_cast<const bf16x8*>(row + 32 * t + lg * 8);
                a0 = __builtin_amdgcn_mfma_f32_16x16x32_bf16(wf[0][t], bf, a0, 0, 0, 0);
            }
            float4 o0;
            o0.x = a0[0] + biasr[0];
            o0.y = a0[1] + biasr[1];
            o0.z = a0[2] + biasr[2];
            o0.w = a0[3] + biasr[3];
            *reinterpret_cast<float4*>(orow + vb) = o0;
        }

        // ===== group B: seg1 — acc live: 12 f32 =====
        {
            f32x4 aB[3];
            #pragma unroll
            for (int j = 0; j < 3; ++j) { f32x4 z = {0.f,0.f,0.f,0.f}; aB[j] = z; }
            #pragma unroll
            for (int t = 0; t < 4; ++t) {
                const int u0 = 32 * t + lg * 8;
                #pragma unroll
                for (int j = 0; j < 3; ++j) {
                    bf16x8 bf = *reinterpret_cast<const bf16x8*>(row + ((1 + j) << 7) + u0);
                    aB[j] = __builtin_amdgcn_mfma_f32_16x16x32_bf16(wf[1][t], bf, aB[j], 0, 0, 0);
                }
            }
            float* p1o = orow + 128 + 3 * vb;   // p=3e+i -> aB[p%3][p/3]
            #pragma unroll
            for (int k = 0; k < 3; ++k) {
                float4 o;
                o.x = aB[(4 * k + 0) % 3][(4 * k + 0) / 3];
                o.y = aB[(4 * k + 1) % 3][(4 * k + 1) / 3];
                o.z = aB[(4 * k + 2) % 3][(4 * k + 2) / 3];
                o.w = aB[(4 * k + 3) % 3][(4 * k + 3) / 3];
                *reinterpret_cast<float4*>(p1o + 4 * k) = o;
            }
        }

        // ---- retire H1 into LDS (loads ~half a tile old); then issue H2 ----
        if (has_next) {
            STAGE_WRITE_H1(cur ^ 1);
            STAGE_LOAD_H2(tile + GRIDSZ);
        }

        // ===== group C: seg2 — acc live: 20 f32 =====
        {
            f32x4 aC[5];
            #pragma unroll
            for (int j = 0; j < 5; ++j) { f32x4 z = {0.f,0.f,0.f,0.f}; aC[j] = z; }
            #pragma unroll
            for (int t = 0; t < 4; ++t) {
                const int u0 = 32 * t + lg * 8;
                #pragma unroll
                for (int j = 0; j < 5; ++j) {
                    bf16x8 bf = *reinterpret_cast<const bf16x8*>(row + ((4 + j) << 7) + u0);
                    aC[j] = __builtin_amdgcn_mfma_f32_16x16x32_bf16(wf[2][t], bf, aC[j], 0, 0, 0);
                }
            }
            float* p2o = orow + 512 + 5 * vb;   // p=5e+i -> aC[p%5][p/5]
            #pragma unroll
            for (int k = 0; k < 5; ++k) {
                float4 o;
                o.x = aC[(4 * k + 0) % 5][(4 * k + 0) / 5];
                o.y = aC[(4 * k + 1) % 5][(4 * k + 1) / 5];
                o.z = aC[(4 * k + 2) % 5][(4 * k + 2) / 5];
                o.w = aC[(4 * k + 3) % 5][(4 * k + 3) / 5];
                *reinterpret_cast<float4*>(p2o + 4 * k) = o;
            }
        }

        // ---- retire H2 into LDS (loads ~half a tile old) ----
        if (has_next) STAGE_WRITE_H2(cur ^ 1);

        // Relaxed barrier: only LDS ops must drain; global loads/stores keep
        // flowing across it (counted-vmcnt discipline).
        asm volatile("s_waitcnt lgkmcnt(0)\n\ts_barrier" ::: "memory");
        cur ^= 1;
    }
#undef STAGE_LOAD_H1
#undef STAGE_LOAD_H2
#undef STAGE_WRITE_H1
#undef STAGE_WRITE_H2
}

extern "C" void kernel_launch(void* const* d_in, const int* in_sizes, int n_in,
                              void* d_out, int out_size, void* d_ws, size_t ws_size,
                              hipStream_t stream) {
    const float* x = (const float*)d_in[0];
    const float* w = (const float*)d_in[1];
    const float* b = (const float*)d_in[2];
    float* outp = (float*)d_out;
    seglin_kernel<<<dim3(GRIDSZ), dim3(512), 0, stream>>>(x, w, b, outp);
}

// Round 13
// 193.329 us; speedup vs baseline: 1.3693x; 1.3693x over previous
//
#include <hip/hip_runtime.h>

typedef __attribute__((ext_vector_type(8))) short bf16x8;
typedef __attribute__((ext_vector_type(4))) float f32x4;

#define NBLK   16          // nodes per tile
#define DIMF   1152        // floats per node row
#define NTILE  6250        // 100000 / 16, exact
#define GRIDSZ 512         // persistent, stride grid
#define ROWU   1168        // padded ushort row stride: 2336 B == 8 dwords mod 32
                           // -> ds_read_b128 bank = (8*lq+4*lg)%32, 2-way max (free)

// round-to-nearest-even f32 -> bf16 bits (host-side W/bias only)
static __device__ __forceinline__ unsigned short f2bf(float f) {
    unsigned int u = __builtin_bit_cast(unsigned int, f);
    return (unsigned short)((u + 0x7FFFu + ((u >> 16) & 1u)) >> 16);
}

// packed RNE convert: low16 = bf16(lo), high16 = bf16(hi) — 1 VALU op for 2 values
static __device__ __forceinline__ unsigned int cvtpk(float lo, float hi) {
    unsigned int r;
    asm("v_cvt_pk_bf16_f32 %0, %1, %2" : "=v"(r) : "v"(lo), "v"(hi));
    return r;
}

__global__ __launch_bounds__(512, 2)
void seglin_kernel(const float* __restrict__ x, const float* __restrict__ w,
                   const float* __restrict__ b, float* __restrict__ out) {
    // LDS: per node, 9 planes of 128 u-contiguous bf16
    //   plane 0 = seg0; planes 1..3 = seg1 (base 128+i*128); planes 4..8 = seg2 (base 512+i*128)
    __shared__ unsigned short xs[2][NBLK][ROWU];

    const int tid  = threadIdx.x;
    const int wv   = tid >> 6;
    const int lane = tid & 63;
    const int lq   = lane & 15;       // node col n (B); A row v_local (W frags)
    const int lg   = lane >> 4;       // k-group 0..3
    const int v0   = wv * 16;

    const int sn = tid >> 5;          // staging node 0..15
    const int st = tid & 31;          // staging u-chunk 0..31

    const float pw = 0.08838834764831845f;  // 128^-0.5, folded into W

    // ---- hoist A = pw * W^T fragments (once per block) ----
    bf16x8 wf[3][4];
    const int woff[3] = {0, 16384, 32768};
    #pragma unroll
    for (int s = 0; s < 3; ++s)
        #pragma unroll
        for (int t = 0; t < 4; ++t) {
            bf16x8 f;
            #pragma unroll
            for (int e = 0; e < 8; ++e) {
                int u = 32 * t + lg * 8 + e;
                f[e] = (short)f2bf(pw * w[woff[s] + u * 128 + v0 + lq]);
            }
            wf[s][t] = f;
        }

    float biasr[4];
    #pragma unroll
    for (int e = 0; e < 4; ++e) biasr[e] = b[v0 + lg * 4 + e];

    // Staged tile: 36 f32 loaded at loop-TOP (latency hidden under compute),
    // consumed at loop-END (STAGE_WRITE). Do not alter this timing (R9/R10).
    float4 g0, g1[3], g2[5];

#define STAGE_LOAD(TILE) do {                                                   \
        const float* src = x + ((long)(TILE) * NBLK + sn) * DIMF;               \
        g0    = *reinterpret_cast<const float4*>(src + 4 * st);                 \
        g1[0] = *reinterpret_cast<const float4*>(src + 128 + 12 * st);          \
        g1[1] = *reinterpret_cast<const float4*>(src + 128 + 12 * st + 4);      \
        g1[2] = *reinterpret_cast<const float4*>(src + 128 + 12 * st + 8);      \
        g2[0] = *reinterpret_cast<const float4*>(src + 512 + 20 * st);          \
        g2[1] = *reinterpret_cast<const float4*>(src + 512 + 20 * st + 4);      \
        g2[2] = *reinterpret_cast<const float4*>(src + 512 + 20 * st + 8);      \
        g2[3] = *reinterpret_cast<const float4*>(src + 512 + 20 * st + 12);     \
        g2[4] = *reinterpret_cast<const float4*>(src + 512 + 20 * st + 16);     \
    } while (0)

    // Plane p, pos u=4st+e:  seg1 plane i takes f1[3e+i]; seg2 plane i takes f2[5e+i].
    // Each plane's 4 values -> 2 v_cvt_pk_bf16_f32 -> one uint2 (8B) LDS write.
#define STAGE_WRITE(BUF) do {                                                   \
        unsigned short* dst = &xs[BUF][sn][0];                                  \
        { uint2 h; h.x = cvtpk(g0.x, g0.y); h.y = cvtpk(g0.z, g0.w);            \
          *reinterpret_cast<uint2*>(dst + 4 * st) = h; }                        \
        float f1[12];                                                           \
        f1[0]=g1[0].x; f1[1]=g1[0].y; f1[2]=g1[0].z; f1[3]=g1[0].w;             \
        f1[4]=g1[1].x; f1[5]=g1[1].y; f1[6]=g1[1].z; f1[7]=g1[1].w;             \
        f1[8]=g1[2].x; f1[9]=g1[2].y; f1[10]=g1[2].z; f1[11]=g1[2].w;           \
        _Pragma("unroll")                                                       \
        for (int i = 0; i < 3; ++i) {                                           \
            uint2 h;                                                            \
            h.x = cvtpk(f1[0 + i], f1[3 + i]);                                  \
            h.y = cvtpk(f1[6 + i], f1[9 + i]);                                  \
            *reinterpret_cast<uint2*>(dst + 128 + (i << 7) + 4 * st) = h;       \
        }                                                                       \
        float f2[20];                                                           \
        f2[0]=g2[0].x; f2[1]=g2[0].y; f2[2]=g2[0].z; f2[3]=g2[0].w;             \
        f2[4]=g2[1].x; f2[5]=g2[1].y; f2[6]=g2[1].z; f2[7]=g2[1].w;             \
        f2[8]=g2[2].x; f2[9]=g2[2].y; f2[10]=g2[2].z; f2[11]=g2[2].w;           \
        f2[12]=g2[3].x; f2[13]=g2[3].y; f2[14]=g2[3].z; f2[15]=g2[3].w;         \
        f2[16]=g2[4].x; f2[17]=g2[4].y; f2[18]=g2[4].z; f2[19]=g2[4].w;         \
        _Pragma("unroll")                                                       \
        for (int i = 0; i < 5; ++i) {                                           \
            uint2 h;                                                            \
            h.x = cvtpk(f2[0 + i],  f2[5 + i]);                                 \
            h.y = cvtpk(f2[10 + i], f2[15 + i]);                                \
            *reinterpret_cast<uint2*>(dst + 512 + (i << 7) + 4 * st) = h;       \
        }                                                                       \
    } while (0)

    // ---- prologue ----
    long tile = blockIdx.x;
    STAGE_LOAD(tile);
    STAGE_WRITE(0);
    __syncthreads();

    int cur = 0;
    for (; tile < NTILE; tile += GRIDSZ) {
        const bool has_next = (tile + GRIDSZ) < NTILE;

        // loads for next tile issued FIRST; consumed at loop-end STAGE_WRITE
        if (has_next) STAGE_LOAD(tile + GRIDSZ);

        const unsigned short* row = &xs[cur][lq][0];
        float* orow = out + (tile * NBLK + lq) * (long)DIMF;
        const int vb = v0 + lg * 4;

        // ===== group A: seg0 — acc live: 4 f32 =====
        {
            f32x4 a0 = {0.f, 0.f, 0.f, 0.f};
            #pragma unroll
            for (int t = 0; t < 4; ++t) {
                bf16x8 bf = *reinterpret_cast<const bf16x8*>(row + 32 * t + lg * 8);
                a0 = __builtin_amdgcn_mfma_f32_16x16x32_bf16(wf[0][t], bf, a0, 0, 0, 0);
            }
            float4 o0;
            o0.x = a0[0] + biasr[0];
            o0.y = a0[1] + biasr[1];
            o0.z = a0[2] + biasr[2];
            o0.w = a0[3] + biasr[3];
            *reinterpret_cast<float4*>(orow + vb) = o0;
        }

        // ===== group B: seg1 — acc live: 12 f32 =====
        {
            f32x4 aB[3];
            #pragma unroll
            for (int j = 0; j < 3; ++j) { f32x4 z = {0.f,0.f,0.f,0.f}; aB[j] = z; }
            #pragma unroll
            for (int t = 0; t < 4; ++t) {
                const int u0 = 32 * t + lg * 8;
                #pragma unroll
                for (int j = 0; j < 3; ++j) {
                    bf16x8 bf = *reinterpret_cast<const bf16x8*>(row + ((1 + j) << 7) + u0);
                    aB[j] = __builtin_amdgcn_mfma_f32_16x16x32_bf16(wf[1][t], bf, aB[j], 0, 0, 0);
                }
            }
            float* p1o = orow + 128 + 3 * vb;   // p=3e+i -> aB[p%3][p/3]
            #pragma unroll
            for (int k = 0; k < 3; ++k) {
                float4 o;
                o.x = aB[(4 * k + 0) % 3][(4 * k + 0) / 3];
                o.y = aB[(4 * k + 1) % 3][(4 * k + 1) / 3];
                o.z = aB[(4 * k + 2) % 3][(4 * k + 2) / 3];
                o.w = aB[(4 * k + 3) % 3][(4 * k + 3) / 3];
                *reinterpret_cast<float4*>(p1o + 4 * k) = o;
            }
        }

        // ===== group C: seg2 — acc live: 20 f32 =====
        {
            f32x4 aC[5];
            #pragma unroll
            for (int j = 0; j < 5; ++j) { f32x4 z = {0.f,0.f,0.f,0.f}; aC[j] = z; }
            #pragma unroll
            for (int t = 0; t < 4; ++t) {
                const int u0 = 32 * t + lg * 8;
                #pragma unroll
                for (int j = 0; j < 5; ++j) {
                    bf16x8 bf = *reinterpret_cast<const bf16x8*>(row + ((4 + j) << 7) + u0);
                    aC[j] = __builtin_amdgcn_mfma_f32_16x16x32_bf16(wf[2][t], bf, aC[j], 0, 0, 0);
                }
            }
            float* p2o = orow + 512 + 5 * vb;   // p=5e+i -> aC[p%5][p/5]
            #pragma unroll
            for (int k = 0; k < 5; ++k) {
                float4 o;
                o.x = aC[(4 * k + 0) % 5][(4 * k + 0) / 5];
                o.y = aC[(4 * k + 1) % 5][(4 * k + 1) / 5];
                o.z = aC[(4 * k + 2) % 5][(4 * k + 2) / 5];
                o.w = aC[(4 * k + 3) % 5][(4 * k + 3) / 5];
                *reinterpret_cast<float4*>(p2o + 4 * k) = o;
            }
        }

        // ---- retire staged regs into LDS (loads issued a full period ago) ----
        if (has_next) STAGE_WRITE(cur ^ 1);

        // Relaxed barrier: only LDS ops must drain; global loads/stores keep
        // flowing across it (counted-vmcnt discipline).
        asm volatile("s_waitcnt lgkmcnt(0)\n\ts_barrier" ::: "memory");
        cur ^= 1;
    }
#undef STAGE_LOAD
#undef STAGE_WRITE
}

extern "C" void kernel_launch(void* const* d_in, const int* in_sizes, int n_in,
                              void* d_out, int out_size, void* d_ws, size_t ws_size,
                              hipStream_t stream) {
    const float* x = (const float*)d_in[0];
    const float* w = (const float*)d_in[1];
    const float* b = (const float*)d_in[2];
    float* outp = (float*)d_out;
    seglin_kernel<<<dim3(GRIDSZ), dim3(512), 0, stream>>>(x, w, b, outp);
}